// Round 20
// baseline (101.279 us; speedup 1.0000x reference)
//
#include <hip/hip_runtime.h>

struct PrepPtrs {
  const float* W[7]; const float* Bv[7]; const float* F; const float* fb;
  const float* W8; const float* B8; const float* W9; const float* B9;
  const float* W10; const float* B10;
};

// state-chunk swizzle (LDS kernels): fold bits 3-4 into bits 0-1.
// cz(pb+1) = cz(pb)^1 for even pb. Linear over +N with no bits 0-5.
__device__ __forceinline__ int cz(int c) { return c ^ ((c >> 3) & 3); }

__device__ __forceinline__ float4 relu4(float4 a) {
  return make_float4(fmaxf(a.x,0.f), fmaxf(a.y,0.f), fmaxf(a.z,0.f), fmaxf(a.w,0.f));
}
__device__ __forceinline__ void fma4(float4& acc, float s, const float4& wv) {
  acc.x = fmaf(s, wv.x, acc.x); acc.y = fmaf(s, wv.y, acc.y);
  acc.z = fmaf(s, wv.z, acc.z); acc.w = fmaf(s, wv.w, acc.w);
}
__device__ __forceinline__ float4 add4(float4 a, float4 b) {
  return make_float4(a.x+b.x, a.y+b.y, a.z+b.z, a.w+b.w);
}

// 4-way-split butterfly apply (4 independent accumulator chains)
__device__ __forceinline__ float4 entApply(const float4* __restrict__ e4,
                                           float4 A0, float4 A1,
                                           float4 C0, float4 C1) {
  float4 a0 = e4[16];
  float4 a1 = make_float4(0.f, 0.f, 0.f, 0.f);
  float4 a2 = make_float4(0.f, 0.f, 0.f, 0.f);
  float4 a3 = make_float4(0.f, 0.f, 0.f, 0.f);
  fma4(a0, A0.x, e4[0]);  fma4(a1, A0.y, e4[1]);  fma4(a2, A0.z, e4[2]);  fma4(a3, A0.w, e4[3]);
  fma4(a0, A1.x, e4[4]);  fma4(a1, A1.y, e4[5]);  fma4(a2, A1.z, e4[6]);  fma4(a3, A1.w, e4[7]);
  fma4(a0, C0.x, e4[8]);  fma4(a1, C0.y, e4[9]);  fma4(a2, C0.z, e4[10]); fma4(a3, C0.w, e4[11]);
  fma4(a0, C1.x, e4[12]); fma4(a1, C1.y, e4[13]); fma4(a2, C1.z, e4[14]); fma4(a3, C1.w, e4[15]);
  return relu4(add4(add4(a0, a1), add4(a2, a3)));
}

// ---------------- prep: pack ALL weights into 80-float (k,th) entries (unchanged) ------
__global__ void bfly_prep(PrepPtrs P, float* __restrict__ wt) {
  int e = blockIdx.x * 256 + threadIdx.x;
  if (e >= 4094 * 68) return;
  int ent = e / 68, r = e % 68, dd = r & 3;
  const float* Ws; const float* Bs; int th;
  if (ent < 62) {
    if (ent < 60) {
      int lvl, base;
      if (ent < 4)       { lvl = 1; base = 0;  }
      else if (ent < 12) { lvl = 2; base = 4;  }
      else if (ent < 28) { lvl = 3; base = 12; }
      else               { lvl = 4; base = 28; }
      int k = (ent - base) >> 1; th = ent & 1;
      Ws = P.W[lvl-1] + k*128; Bs = P.Bv[lvl-1] + k*8;
    } else {
      th = ent - 60; Ws = P.F; Bs = P.fb;
    }
  } else if (ent < 510) {
    int eb = ent - 62;
    int q = eb / 56, rem = eb % 56;
    int lvl, Kl, base;
    if (rem < 8)       { lvl = 5; Kl = 4;  base = 0;  }
    else if (rem < 24) { lvl = 6; Kl = 8;  base = 8;  }
    else               { lvl = 7; Kl = 16; base = 24; }
    int rr = rem - base; int lk = rr >> 1; th = rr & 1;
    int kg = q * Kl + lk;
    Ws = P.W[lvl-1] + kg*128; Bs = P.Bv[lvl-1] + kg*8;
  } else if (ent < 1022) {
    int ec = ent - 510; int k = ec >> 1; th = ec & 1;
    Ws = P.W8 + k*128; Bs = P.B8 + k*8;
  } else if (ent < 2046) {
    int ec = ent - 1022; int k = ec >> 1; th = ec & 1;
    Ws = P.W9 + k*128; Bs = P.B9 + k*8;
  } else {
    int ec = ent - 2046; int k = ec >> 1; th = ec & 1;
    Ws = P.W10 + k*128; Bs = P.B10 + k*8;
  }
  float v;
  if (r < 64) { int s = r >> 5, c = (r >> 2) & 7; v = Ws[s*64 + c*8 + th*4 + dd]; }
  else v = Bs[th*4 + dd];
  wt[ent * 80 + r] = v;
}

// ---------------- KA: conv + L1..L3 FULLY IN REGISTERS ----------------
// 128 threads/batch; thread owns 8 consecutive leaves [8T, 8T+8) — the complete
// sub-forest through level 3 (8 rows per level, all parents thread-local).
// No LDS, no barriers. Weights via wave-uniform s_load (all lanes at the same
// unrolled (th,k) position). State: s[16]+n[16] f4 ping-pong, static indices only.
__global__ __launch_bounds__(256, 2) void bfly_ka(
    const float* __restrict__ x, const float* __restrict__ wt,
    float* __restrict__ st1)
{
  const int tid = threadIdx.x;
  const int T = tid & 127;            // leaf-block index within batch
  const int bb = tid >> 7;            // 2 batches per 256-thr block
  const int b = blockIdx.x * 2 + bb;
  const float4* wt4 = (const float4*)wt;
  const float4* xb4 = (const float4*)x + (size_t)b * 4096 + T * 32;

  float4 s[16], n[16];

  // conv (kernel=16, stride=16): s[r*2+th] for leaf-rows r in [0,8)
#pragma unroll
  for (int th = 0; th < 2; ++th) {
    const float4* e4 = wt4 + (60 + th) * 20;
#pragma unroll
    for (int r = 0; r < 8; ++r) {
      float4 x0 = xb4[r*4], x1 = xb4[r*4+1], x2 = xb4[r*4+2], x3 = xb4[r*4+3];
      s[r*2+th] = entApply(e4, x0, x1, x2, x3);
    }
  }
  // L1: n[(k*4+t)*2+th] <- parents s rows (2t, 2t+1)
#pragma unroll
  for (int th = 0; th < 2; ++th)
#pragma unroll
    for (int k = 0; k < 2; ++k) {
      const float4* e4 = wt4 + (0 + k*2 + th) * 20;
#pragma unroll
      for (int t = 0; t < 4; ++t)
        n[(k*4+t)*2+th] = entApply(e4, s[(2*t)*2], s[(2*t)*2+1],
                                       s[(2*t+1)*2], s[(2*t+1)*2+1]);
    }
  // L2: s[(k*2+t)*2+th] <- parents n rows ((k>>1)*4+2t, +1)
#pragma unroll
  for (int th = 0; th < 2; ++th)
#pragma unroll
    for (int k = 0; k < 4; ++k) {
      const float4* e4 = wt4 + (4 + k*2 + th) * 20;
      const int kp = k >> 1;
#pragma unroll
      for (int t = 0; t < 2; ++t)
        s[(k*2+t)*2+th] = entApply(e4, n[(kp*4+2*t)*2], n[(kp*4+2*t)*2+1],
                                       n[(kp*4+2*t+1)*2], n[(kp*4+2*t+1)*2+1]);
    }
  // L3: n[k*2+th] <- parents s rows ((k>>1)*2 + 0, 1)
#pragma unroll
  for (int th = 0; th < 2; ++th)
#pragma unroll
    for (int k = 0; k < 8; ++k) {
      const float4* e4 = wt4 + (12 + k*2 + th) * 20;
      const int kp = k >> 1;
      n[k*2+th] = entApply(e4, s[(kp*2)*2], s[(kp*2)*2+1],
                               s[(kp*2+1)*2], s[(kp*2+1)*2+1]);
    }
  // write st1[k3][th][b][t3]: lane = T consecutive -> coalesced 1KB runs
  float4* o4 = (float4*)st1;
#pragma unroll
  for (int k = 0; k < 8; ++k)
#pragma unroll
    for (int th = 0; th < 2; ++th)
      o4[((size_t)(k*2+th) * 1024 + b) * 128 + T] = n[k*2+th];
}

// ---------------- KB: levels 4..7, IN-PLACE single 32KB buffer ----------------
template<int LV>
__device__ __forceinline__ void kb_level2(float4* __restrict__ s,
                                          const float4* __restrict__ wb4,
                                          int lane, int w) {
  constexpr int Tc = 1 << (10 - LV);        // 32,16,8
  constexpr int entB = (LV == 5) ? 0 : (LV == 6) ? 8 : 24;
  int kp, bl, t;
  if constexpr (LV == 5)      { kp = w >> 2; bl = ((w & 3) << 1) | (lane >> 5); t = lane & 31; }
  else if constexpr (LV == 6) { kp = w >> 1; bl = ((w & 1) << 2) | (lane >> 4); t = lane & 15; }
  else                        { kp = w;      bl = lane >> 3;                    t = lane & 7;  }
  const int pb = bl * 256 + kp * (2 * Tc) + 2 * t;   // even
  const int cb = cz(pb);
  const int cb1 = cb ^ 1;
  float4 A0 = s[cb],       C0 = s[cb1];
  float4 A1 = s[cb + 128], C1 = s[cb1 + 128];
#pragma unroll
  for (int kk = 0; kk < 2; ++kk) {
    float4* pD = s + cz(bl * 256 + (2 * kp + kk) * Tc + t);
#pragma unroll
    for (int th = 0; th < 2; ++th) {
      const float4* e4 = wb4 + (entB + (2 * kp + kk) * 2 + th) * 20;  // uniform s_load
      pD[th * 128] = entApply(e4, A0, A1, C0, C1);
    }
  }
}

__global__ __launch_bounds__(512, 3) void bfly_kb(
    const float* __restrict__ st1, const float* __restrict__ wt,
    float* __restrict__ st2)
{
  __shared__ float4 s0[2048];                // single buffer, in-place levels
  const int tid = threadIdx.x;
  const int q = blockIdx.x, bt = blockIdx.y; // q = level-3 branch [0,8)
  const int lane = tid & 63;
  const int w = __builtin_amdgcn_readfirstlane(tid >> 6);
  const float4* wt4 = (const float4*)wt;
  const float4* wb4 = wt4 + 1240 + q * 56 * 20;
  const float4* i4 = (const float4*)st1;

  // stage level-3 state of branch q: frame row = t3 in [0,128)
#pragma unroll
  for (int it = 0; it < 4; ++it) {
    int o = tid + it * 512;
    int t3 = o & 127, h = (o >> 7) & 1, bl = o >> 8;
    float4 v = i4[((size_t)(q * 2 + h) * 1024 + bt * 8 + bl) * 128 + t3];
    s0[cz(bl * 256 + h * 128 + t3)] = v;
  }
  __syncthreads();
  { // level 4: global k4 = 2q+kk; wave w = batch bl, lane = t4 in [0,64)
    const float4* eb = wt4 + (28 + 4 * q) * 20;
    int bl = w, t = lane;
    int pb = bl * 256 + 2 * t;
    int cb = cz(pb), cb1 = cb ^ 1;
    float4 A0 = s0[cb], C0 = s0[cb1], A1 = s0[cb + 128], C1 = s0[cb1 + 128];
#pragma unroll
    for (int kk = 0; kk < 2; ++kk) {
      float4* pD = s0 + cz(bl * 256 + kk * 64 + t);
#pragma unroll
      for (int th = 0; th < 2; ++th) {
        const float4* e4 = eb + (kk * 2 + th) * 20;   // uniform s_load
        pD[th * 128] = entApply(e4, A0, A1, C0, C1);
      }
    }
  }
  __syncthreads();
  kb_level2<5>(s0, wb4, lane, w); __syncthreads();
  kb_level2<6>(s0, wb4, lane, w); __syncthreads();
  kb_level2<7>(s0, wb4, lane, w); __syncthreads();

  float4* o4 = (float4*)st2;
#pragma unroll
  for (int it = 0; it < 4; ++it) {
    int o = tid + it * 512;
    int bl = o & 7, t7 = (o >> 3) & 7, h = (o >> 6) & 1, lk7 = o >> 7;
    float4 v = s0[cz(bl * 256 + h * 128 + lk7 * 8 + t7)];
    o4[((size_t)((16 * q + lk7) * 8 + t7) * 2 + h) * 1024 + bt * 8 + bl] = v;
  }
}

// ---------------- KC: levels 8..10 + dense, all-SGPR weights (R18-proven) ----------
__global__ __launch_bounds__(512, 2) void bfly_kc(
    const float* __restrict__ st, const float* __restrict__ wt,
    const float* __restrict__ fea, float* __restrict__ out)
{
  __shared__ float4 sA[1024], sB[1024];
  const int tid = threadIdx.x;
  const int j = blockIdx.x, b0 = blockIdx.y * 64;
  const int bb = tid & 63;
  const int w = __builtin_amdgcn_readfirstlane(tid >> 6);
  const float4* wt4 = (const float4*)wt;

  {
    const float4* s4 = (const float4*)st;
#pragma unroll
    for (int it = 0; it < 2; ++it) {
      int idx = tid + it * 512;
      int bl = idx & 63, h = (idx >> 6) & 1, t = idx >> 7;
      sA[h * 512 + t * 64 + bl] = s4[((size_t)((j * 8 + t) * 2 + h)) * 1024 + b0 + bl];
    }
  }
  __syncthreads();

#pragma unroll
  for (int ii = 0; ii < 2; ++ii) {
    int s = w + ii * 8;
    int th = s >> 3, k = (s >> 2) & 1, t = s & 3;
    const float4* e4 = wt4 + (510 + (2 * j + k) * 2 + th) * 20;
    float4 A0 = sA[(2*t) * 64 + bb],   A1 = sA[512 + (2*t) * 64 + bb];
    float4 C0 = sA[(2*t+1) * 64 + bb], C1 = sA[512 + (2*t+1) * 64 + bb];
    sB[th * 512 + (2*t + k) * 64 + bb] = entApply(e4, A0, A1, C0, C1);
  }
  __syncthreads();
#pragma unroll
  for (int ii = 0; ii < 2; ++ii) {
    int s = w + ii * 8;
    int th = s >> 3, k9 = (s >> 1) & 3, t9 = s & 1;
    const float4* e4 = wt4 + (1022 + (4 * j + k9) * 2 + th) * 20;
    int p0 = 4 * t9 + (k9 >> 1), p1 = p0 + 2;
    float4 A0 = sB[p0 * 64 + bb], A1 = sB[512 + p0 * 64 + bb];
    float4 C0 = sB[p1 * 64 + bb], C1 = sB[512 + p1 * 64 + bb];
    sA[th * 512 + (t9 * 4 + k9) * 64 + bb] = entApply(e4, A0, A1, C0, C1);
  }
  __syncthreads();
#pragma unroll
  for (int ii = 0; ii < 2; ++ii) {
    int s = w + ii * 8;
    int th = s >> 3, k10 = s & 7;
    const float4* e4 = wt4 + (2046 + (8 * j + k10) * 2 + th) * 20;
    int p0 = k10 >> 1, p1 = p0 + 4;
    float4 A0 = sA[p0 * 64 + bb], A1 = sA[512 + p0 * 64 + bb];
    float4 C0 = sA[p1 * 64 + bb], C1 = sA[512 + p1 * 64 + bb];
    sB[th * 512 + k10 * 64 + bb] = entApply(e4, A0, A1, C0, C1);
  }
  __syncthreads();
  {
    int cc = tid & 31, bgrp = tid >> 5;
    int k = cc >> 2, fq = cc & 3;
    const float* fp = fea + (size_t)(j * 8 + k) * 128 + fq * 4;
    float4 f0 = *(const float4*)(fp);        float4 f1 = *(const float4*)(fp + 16);
    float4 f2 = *(const float4*)(fp + 32);   float4 f3 = *(const float4*)(fp + 48);
    float4 f4_ = *(const float4*)(fp + 64);  float4 f5 = *(const float4*)(fp + 80);
    float4 f6 = *(const float4*)(fp + 96);   float4 f7 = *(const float4*)(fp + 112);
#pragma unroll
    for (int it = 0; it < 4; ++it) {
      int b_l = bgrp + it * 16;
      float4 s0v = sB[k * 64 + b_l];
      float4 s1v = sB[512 + k * 64 + b_l];
      float4 a0 = make_float4(0.f,0.f,0.f,0.f), a1 = make_float4(0.f,0.f,0.f,0.f);
      float4 a2 = make_float4(0.f,0.f,0.f,0.f), a3 = make_float4(0.f,0.f,0.f,0.f);
      fma4(a0, s0v.x, f0);  fma4(a1, s0v.y, f1);
      fma4(a2, s0v.z, f2);  fma4(a3, s0v.w, f3);
      fma4(a0, s1v.x, f4_); fma4(a1, s1v.y, f5);
      fma4(a2, s1v.z, f6);  fma4(a3, s1v.w, f7);
      float4 acc = add4(add4(a0, a1), add4(a2, a3));
      *(float4*)(out + ((size_t)(b0 + b_l)) * 16384 + j * 128 + k * 16 + fq * 4) = acc;
    }
  }
}

extern "C" void kernel_launch(void* const* d_in, const int* in_sizes, int n_in,
                              void* d_out, int out_size, void* d_ws, size_t ws_size,
                              hipStream_t stream) {
  const float* x  = (const float*)d_in[0];
  PrepPtrs P;
  P.F  = (const float*)d_in[1];
  P.fb = (const float*)d_in[2];
  for (int l = 0; l < 7; ++l) {
    P.W[l]  = (const float*)d_in[3 + 2 * l];
    P.Bv[l] = (const float*)d_in[4 + 2 * l];
  }
  P.W8  = (const float*)d_in[17];
  P.B8  = (const float*)d_in[18];
  P.W9  = (const float*)d_in[19];
  P.B9  = (const float*)d_in[20];
  P.W10 = (const float*)d_in[21];
  P.B10 = (const float*)d_in[22];
  const float* fea = (const float*)d_in[23];
  float* wt  = (float*)d_ws;                 // 4094 entries x 80 floats = 1.31 MB
  float* st2 = (float*)d_ws + 393216;        // 33.5 MB level-7 state [j][t][h][b]
  float* st1 = (float*)d_out;                // 32 MB level-3 state (KC overwrites d_out)
  float* out = (float*)d_out;

  bfly_prep<<<dim3(1088), dim3(256), 0, stream>>>(P, wt);
  bfly_ka<<<dim3(512), dim3(256), 0, stream>>>(x, wt, st1);
  bfly_kb<<<dim3(8, 128), dim3(512), 0, stream>>>(st1, wt, st2);
  bfly_kc<<<dim3(128, 16), dim3(512), 0, stream>>>(st2, wt, fea, out);
}

// Round 21
// 96.440 us; speedup vs baseline: 1.0502x; 1.0502x over previous
//
#include <hip/hip_runtime.h>

struct PrepPtrs {
  const float* W[7]; const float* Bv[7]; const float* F; const float* fb;
  const float* W8; const float* B8; const float* W9; const float* B9;
  const float* W10; const float* B10;
};

// state-chunk swizzle (LDS kernels): fold bits 3-4 into bits 0-1.
// cz(pb+1) = cz(pb)^1 for even pb. Linear over +N with no bits 0-5.
__device__ __forceinline__ int cz(int c) { return c ^ ((c >> 3) & 3); }

__device__ __forceinline__ float4 relu4(float4 a) {
  return make_float4(fmaxf(a.x,0.f), fmaxf(a.y,0.f), fmaxf(a.z,0.f), fmaxf(a.w,0.f));
}
__device__ __forceinline__ void fma4(float4& acc, float s, const float4& wv) {
  acc.x = fmaf(s, wv.x, acc.x); acc.y = fmaf(s, wv.y, acc.y);
  acc.z = fmaf(s, wv.z, acc.z); acc.w = fmaf(s, wv.w, acc.w);
}
__device__ __forceinline__ float4 add4(float4 a, float4 b) {
  return make_float4(a.x+b.x, a.y+b.y, a.z+b.z, a.w+b.w);
}

// 4-way-split butterfly apply (4 independent accumulator chains)
__device__ __forceinline__ float4 entApply(const float4* __restrict__ e4,
                                           float4 A0, float4 A1,
                                           float4 C0, float4 C1) {
  float4 a0 = e4[16];
  float4 a1 = make_float4(0.f, 0.f, 0.f, 0.f);
  float4 a2 = make_float4(0.f, 0.f, 0.f, 0.f);
  float4 a3 = make_float4(0.f, 0.f, 0.f, 0.f);
  fma4(a0, A0.x, e4[0]);  fma4(a1, A0.y, e4[1]);  fma4(a2, A0.z, e4[2]);  fma4(a3, A0.w, e4[3]);
  fma4(a0, A1.x, e4[4]);  fma4(a1, A1.y, e4[5]);  fma4(a2, A1.z, e4[6]);  fma4(a3, A1.w, e4[7]);
  fma4(a0, C0.x, e4[8]);  fma4(a1, C0.y, e4[9]);  fma4(a2, C0.z, e4[10]); fma4(a3, C0.w, e4[11]);
  fma4(a0, C1.x, e4[12]); fma4(a1, C1.y, e4[13]); fma4(a2, C1.z, e4[14]); fma4(a3, C1.w, e4[15]);
  return relu4(add4(add4(a0, a1), add4(a2, a3)));
}

// ---------------- prep: pack ALL weights into 80-float (k,th) entries (unchanged) ------
__global__ void bfly_prep(PrepPtrs P, float* __restrict__ wt) {
  int e = blockIdx.x * 256 + threadIdx.x;
  if (e >= 4094 * 68) return;
  int ent = e / 68, r = e % 68, dd = r & 3;
  const float* Ws; const float* Bs; int th;
  if (ent < 62) {
    if (ent < 60) {
      int lvl, base;
      if (ent < 4)       { lvl = 1; base = 0;  }
      else if (ent < 12) { lvl = 2; base = 4;  }
      else if (ent < 28) { lvl = 3; base = 12; }
      else               { lvl = 4; base = 28; }
      int k = (ent - base) >> 1; th = ent & 1;
      Ws = P.W[lvl-1] + k*128; Bs = P.Bv[lvl-1] + k*8;
    } else {
      th = ent - 60; Ws = P.F; Bs = P.fb;
    }
  } else if (ent < 510) {
    int eb = ent - 62;
    int q = eb / 56, rem = eb % 56;
    int lvl, Kl, base;
    if (rem < 8)       { lvl = 5; Kl = 4;  base = 0;  }
    else if (rem < 24) { lvl = 6; Kl = 8;  base = 8;  }
    else               { lvl = 7; Kl = 16; base = 24; }
    int rr = rem - base; int lk = rr >> 1; th = rr & 1;
    int kg = q * Kl + lk;
    Ws = P.W[lvl-1] + kg*128; Bs = P.Bv[lvl-1] + kg*8;
  } else if (ent < 1022) {
    int ec = ent - 510; int k = ec >> 1; th = ec & 1;
    Ws = P.W8 + k*128; Bs = P.B8 + k*8;
  } else if (ent < 2046) {
    int ec = ent - 1022; int k = ec >> 1; th = ec & 1;
    Ws = P.W9 + k*128; Bs = P.B9 + k*8;
  } else {
    int ec = ent - 2046; int k = ec >> 1; th = ec & 1;
    Ws = P.W10 + k*128; Bs = P.B10 + k*8;
  }
  float v;
  if (r < 64) { int s = r >> 5, c = (r >> 2) & 7; v = Ws[s*64 + c*8 + th*4 + dd]; }
  else v = Bs[th*4 + dd];
  wt[ent * 80 + r] = v;
}

// ---------------- KA tail: L3 + st1 write, templated on uniform U (static indices) -----
template<int U>
__device__ __forceinline__ void ka_tail(const float4 (&s)[8], const float4 (&p)[8],
                                        const float4* __restrict__ wt4,
                                        float4* __restrict__ o4, int b, int T) {
  // lo = L2 state at t=2T (u==0 thread's), hi = t=2T+1 (u==1 thread's)
  float4 n8[8];
#pragma unroll
  for (int th = 0; th < 2; ++th)
#pragma unroll
    for (int kl = 0; kl < 4; ++kl) {
      const float4* e4 = wt4 + (12 + 8*U + kl*2 + th) * 20;   // uniform -> s_load
      constexpr int base = 4 * U;                              // kp = 2U + (kl>>1)
      const int kp2 = base + (kl >> 1) * 2;
      float4 A0, A1, C0, C1;
      if constexpr (U == 0) { A0 = s[kp2]; A1 = s[kp2+1]; C0 = p[kp2]; C1 = p[kp2+1]; }
      else                  { A0 = p[kp2]; A1 = p[kp2+1]; C0 = s[kp2]; C1 = s[kp2+1]; }
      n8[kl*2+th] = entApply(e4, A0, A1, C0, C1);
    }
#pragma unroll
  for (int kl = 0; kl < 4; ++kl)
#pragma unroll
    for (int th = 0; th < 2; ++th)
      o4[((size_t)((4*U + kl)*2 + th) * 1024 + b) * 128 + T] = n8[kl*2+th];
}

// ---------------- KA: conv + L1..L3; thread (T,u) owns 4 leaves; u = wave bit ----------
// conv/L1/L2 thread-local in registers; one LDS exchange (u-pair) before L3.
// All weight entries wave-uniform -> s_load. 2x thread count vs R20 -> 16 waves/CU.
__global__ __launch_bounds__(256, 4) void bfly_ka(
    const float* __restrict__ x, const float* __restrict__ wt,
    float* __restrict__ st1)
{
  __shared__ float4 xch[2048];               // 256 thr x 8 f4 = 32 KB
  const int tid = threadIdx.x;
  const int b = blockIdx.x;
  const int lane = tid & 63;
  const int w = __builtin_amdgcn_readfirstlane(tid >> 6);
  const int u = w & 1;                       // wave-uniform half index
  const int T = lane + (w >> 1) * 64;        // [0,128) leaf-group
  const float4* wt4 = (const float4*)wt;
  const float4* xb4 = (const float4*)x + (size_t)b * 4096 + T * 32 + u * 16;

  float4 s[8], n8[8];
  // conv: 4 rows (global leaf 8T+4u+r) -> s[r*2+th]
#pragma unroll
  for (int r = 0; r < 4; ++r) {
    float4 x0 = xb4[r*4], x1 = xb4[r*4+1], x2 = xb4[r*4+2], x3 = xb4[r*4+3];
#pragma unroll
    for (int th = 0; th < 2; ++th) {
      const float4* e4 = wt4 + (60 + th) * 20;
      s[r*2+th] = entApply(e4, x0, x1, x2, x3);
    }
  }
  // L1: children (k in [0,2), tl in [0,2)) -> n8[(k*2+tl)*2+th]; parents conv rows 2tl,2tl+1
#pragma unroll
  for (int th = 0; th < 2; ++th)
#pragma unroll
    for (int k = 0; k < 2; ++k) {
      const float4* e4 = wt4 + (k*2 + th) * 20;
#pragma unroll
      for (int tl = 0; tl < 2; ++tl)
        n8[(k*2+tl)*2+th] = entApply(e4, s[(2*tl)*2], s[(2*tl)*2+1],
                                         s[(2*tl+1)*2], s[(2*tl+1)*2+1]);
    }
  // L2: children k in [0,4) (single t = 2T+u) -> s[k*2+th]; parents L1 rows (kp,0),(kp,1)
#pragma unroll
  for (int th = 0; th < 2; ++th)
#pragma unroll
    for (int k = 0; k < 4; ++k) {
      const float4* e4 = wt4 + (4 + k*2 + th) * 20;
      const int kp = k >> 1;
      s[k*2+th] = entApply(e4, n8[(kp*2)*2], n8[(kp*2)*2+1],
                               n8[(kp*2+1)*2], n8[(kp*2+1)*2+1]);
    }
  // exchange u-pair via LDS (XOR-swizzled: lane-consecutive T spreads banks)
#pragma unroll
  for (int i = 0; i < 8; ++i)
    xch[T*16 + u*8 + (i ^ (T & 7))] = s[i];
  __syncthreads();
  float4 p[8];
#pragma unroll
  for (int i = 0; i < 8; ++i)
    p[i] = xch[T*16 + (1-u)*8 + (i ^ (T & 7))];

  float4* o4 = (float4*)st1;
  if (u == 0) ka_tail<0>(s, p, wt4, o4, b, T);   // uniform branch
  else        ka_tail<1>(s, p, wt4, o4, b, T);
}

// ---------------- KB: levels 4..7, IN-PLACE single 32KB buffer (R20, validated) --------
template<int LV>
__device__ __forceinline__ void kb_level2(float4* __restrict__ s,
                                          const float4* __restrict__ wb4,
                                          int lane, int w) {
  constexpr int Tc = 1 << (10 - LV);        // 32,16,8
  constexpr int entB = (LV == 5) ? 0 : (LV == 6) ? 8 : 24;
  int kp, bl, t;
  if constexpr (LV == 5)      { kp = w >> 2; bl = ((w & 3) << 1) | (lane >> 5); t = lane & 31; }
  else if constexpr (LV == 6) { kp = w >> 1; bl = ((w & 1) << 2) | (lane >> 4); t = lane & 15; }
  else                        { kp = w;      bl = lane >> 3;                    t = lane & 7;  }
  const int pb = bl * 256 + kp * (2 * Tc) + 2 * t;   // even
  const int cb = cz(pb);
  const int cb1 = cb ^ 1;
  float4 A0 = s[cb],       C0 = s[cb1];
  float4 A1 = s[cb + 128], C1 = s[cb1 + 128];
#pragma unroll
  for (int kk = 0; kk < 2; ++kk) {
    float4* pD = s + cz(bl * 256 + (2 * kp + kk) * Tc + t);
#pragma unroll
    for (int th = 0; th < 2; ++th) {
      const float4* e4 = wb4 + (entB + (2 * kp + kk) * 2 + th) * 20;  // uniform s_load
      pD[th * 128] = entApply(e4, A0, A1, C0, C1);
    }
  }
}

__global__ __launch_bounds__(512, 3) void bfly_kb(
    const float* __restrict__ st1, const float* __restrict__ wt,
    float* __restrict__ st2)
{
  __shared__ float4 s0[2048];                // single buffer, in-place levels
  const int tid = threadIdx.x;
  const int q = blockIdx.x, bt = blockIdx.y; // q = level-3 branch [0,8)
  const int lane = tid & 63;
  const int w = __builtin_amdgcn_readfirstlane(tid >> 6);
  const float4* wt4 = (const float4*)wt;
  const float4* wb4 = wt4 + 1240 + q * 56 * 20;
  const float4* i4 = (const float4*)st1;

  // stage level-3 state of branch q: frame row = t3 in [0,128)
#pragma unroll
  for (int it = 0; it < 4; ++it) {
    int o = tid + it * 512;
    int t3 = o & 127, h = (o >> 7) & 1, bl = o >> 8;
    float4 v = i4[((size_t)(q * 2 + h) * 1024 + bt * 8 + bl) * 128 + t3];
    s0[cz(bl * 256 + h * 128 + t3)] = v;
  }
  __syncthreads();
  { // level 4: global k4 = 2q+kk; wave w = batch bl, lane = t4 in [0,64)
    const float4* eb = wt4 + (28 + 4 * q) * 20;
    int bl = w, t = lane;
    int pb = bl * 256 + 2 * t;
    int cb = cz(pb), cb1 = cb ^ 1;
    float4 A0 = s0[cb], C0 = s0[cb1], A1 = s0[cb + 128], C1 = s0[cb1 + 128];
#pragma unroll
    for (int kk = 0; kk < 2; ++kk) {
      float4* pD = s0 + cz(bl * 256 + kk * 64 + t);
#pragma unroll
      for (int th = 0; th < 2; ++th) {
        const float4* e4 = eb + (kk * 2 + th) * 20;   // uniform s_load
        pD[th * 128] = entApply(e4, A0, A1, C0, C1);
      }
    }
  }
  __syncthreads();
  kb_level2<5>(s0, wb4, lane, w); __syncthreads();
  kb_level2<6>(s0, wb4, lane, w); __syncthreads();
  kb_level2<7>(s0, wb4, lane, w); __syncthreads();

  float4* o4 = (float4*)st2;
#pragma unroll
  for (int it = 0; it < 4; ++it) {
    int o = tid + it * 512;
    int bl = o & 7, t7 = (o >> 3) & 7, h = (o >> 6) & 1, lk7 = o >> 7;
    float4 v = s0[cz(bl * 256 + h * 128 + lk7 * 8 + t7)];
    o4[((size_t)((16 * q + lk7) * 8 + t7) * 2 + h) * 1024 + bt * 8 + bl] = v;
  }
}

// ---------------- KC: levels 8..10 + dense, all-SGPR weights (R18-proven) ----------
__global__ __launch_bounds__(512, 2) void bfly_kc(
    const float* __restrict__ st, const float* __restrict__ wt,
    const float* __restrict__ fea, float* __restrict__ out)
{
  __shared__ float4 sA[1024], sB[1024];
  const int tid = threadIdx.x;
  const int j = blockIdx.x, b0 = blockIdx.y * 64;
  const int bb = tid & 63;
  const int w = __builtin_amdgcn_readfirstlane(tid >> 6);
  const float4* wt4 = (const float4*)wt;

  {
    const float4* s4 = (const float4*)st;
#pragma unroll
    for (int it = 0; it < 2; ++it) {
      int idx = tid + it * 512;
      int bl = idx & 63, h = (idx >> 6) & 1, t = idx >> 7;
      sA[h * 512 + t * 64 + bl] = s4[((size_t)((j * 8 + t) * 2 + h)) * 1024 + b0 + bl];
    }
  }
  __syncthreads();

#pragma unroll
  for (int ii = 0; ii < 2; ++ii) {
    int s = w + ii * 8;
    int th = s >> 3, k = (s >> 2) & 1, t = s & 3;
    const float4* e4 = wt4 + (510 + (2 * j + k) * 2 + th) * 20;
    float4 A0 = sA[(2*t) * 64 + bb],   A1 = sA[512 + (2*t) * 64 + bb];
    float4 C0 = sA[(2*t+1) * 64 + bb], C1 = sA[512 + (2*t+1) * 64 + bb];
    sB[th * 512 + (2*t + k) * 64 + bb] = entApply(e4, A0, A1, C0, C1);
  }
  __syncthreads();
#pragma unroll
  for (int ii = 0; ii < 2; ++ii) {
    int s = w + ii * 8;
    int th = s >> 3, k9 = (s >> 1) & 3, t9 = s & 1;
    const float4* e4 = wt4 + (1022 + (4 * j + k9) * 2 + th) * 20;
    int p0 = 4 * t9 + (k9 >> 1), p1 = p0 + 2;
    float4 A0 = sB[p0 * 64 + bb], A1 = sB[512 + p0 * 64 + bb];
    float4 C0 = sB[p1 * 64 + bb], C1 = sB[512 + p1 * 64 + bb];
    sA[th * 512 + (t9 * 4 + k9) * 64 + bb] = entApply(e4, A0, A1, C0, C1);
  }
  __syncthreads();
#pragma unroll
  for (int ii = 0; ii < 2; ++ii) {
    int s = w + ii * 8;
    int th = s >> 3, k10 = s & 7;
    const float4* e4 = wt4 + (2046 + (8 * j + k10) * 2 + th) * 20;
    int p0 = k10 >> 1, p1 = p0 + 4;
    float4 A0 = sA[p0 * 64 + bb], A1 = sA[512 + p0 * 64 + bb];
    float4 C0 = sA[p1 * 64 + bb], C1 = sA[512 + p1 * 64 + bb];
    sB[th * 512 + k10 * 64 + bb] = entApply(e4, A0, A1, C0, C1);
  }
  __syncthreads();
  {
    int cc = tid & 31, bgrp = tid >> 5;
    int k = cc >> 2, fq = cc & 3;
    const float* fp = fea + (size_t)(j * 8 + k) * 128 + fq * 4;
    float4 f0 = *(const float4*)(fp);        float4 f1 = *(const float4*)(fp + 16);
    float4 f2 = *(const float4*)(fp + 32);   float4 f3 = *(const float4*)(fp + 48);
    float4 f4_ = *(const float4*)(fp + 64);  float4 f5 = *(const float4*)(fp + 80);
    float4 f6 = *(const float4*)(fp + 96);   float4 f7 = *(const float4*)(fp + 112);
#pragma unroll
    for (int it = 0; it < 4; ++it) {
      int b_l = bgrp + it * 16;
      float4 s0v = sB[k * 64 + b_l];
      float4 s1v = sB[512 + k * 64 + b_l];
      float4 a0 = make_float4(0.f,0.f,0.f,0.f), a1 = make_float4(0.f,0.f,0.f,0.f);
      float4 a2 = make_float4(0.f,0.f,0.f,0.f), a3 = make_float4(0.f,0.f,0.f,0.f);
      fma4(a0, s0v.x, f0);  fma4(a1, s0v.y, f1);
      fma4(a2, s0v.z, f2);  fma4(a3, s0v.w, f3);
      fma4(a0, s1v.x, f4_); fma4(a1, s1v.y, f5);
      fma4(a2, s1v.z, f6);  fma4(a3, s1v.w, f7);
      float4 acc = add4(add4(a0, a1), add4(a2, a3));
      *(float4*)(out + ((size_t)(b0 + b_l)) * 16384 + j * 128 + k * 16 + fq * 4) = acc;
    }
  }
}

extern "C" void kernel_launch(void* const* d_in, const int* in_sizes, int n_in,
                              void* d_out, int out_size, void* d_ws, size_t ws_size,
                              hipStream_t stream) {
  const float* x  = (const float*)d_in[0];
  PrepPtrs P;
  P.F  = (const float*)d_in[1];
  P.fb = (const float*)d_in[2];
  for (int l = 0; l < 7; ++l) {
    P.W[l]  = (const float*)d_in[3 + 2 * l];
    P.Bv[l] = (const float*)d_in[4 + 2 * l];
  }
  P.W8  = (const float*)d_in[17];
  P.B8  = (const float*)d_in[18];
  P.W9  = (const float*)d_in[19];
  P.B9  = (const float*)d_in[20];
  P.W10 = (const float*)d_in[21];
  P.B10 = (const float*)d_in[22];
  const float* fea = (const float*)d_in[23];
  float* wt  = (float*)d_ws;                 // 4094 entries x 80 floats = 1.31 MB
  float* st2 = (float*)d_ws + 393216;        // 33.5 MB level-7 state [j][t][h][b]
  float* st1 = (float*)d_out;                // 32 MB level-3 state (KC overwrites d_out)
  float* out = (float*)d_out;

  bfly_prep<<<dim3(1088), dim3(256), 0, stream>>>(P, wt);
  bfly_ka<<<dim3(1024), dim3(256), 0, stream>>>(x, wt, st1);
  bfly_kb<<<dim3(8, 128), dim3(512), 0, stream>>>(st1, wt, st2);
  bfly_kc<<<dim3(128, 16), dim3(512), 0, stream>>>(st2, wt, fea, out);
}